// Round 14
// baseline (399.047 us; speedup 1.0000x reference)
//
#include <hip/hip_runtime.h>
#include <hip/hip_bf16.h>
#include <math.h>

// ---------------------------------------------------------------------------
// RealSymplecticReactionDiffusion2D — round 13
//  B=8, N=4096 (64x64), d=768, k_steps=4 (read from device)
// Stages:
//  1) transpose_x (FUSED column-sum partials for mean-pool) -> xT + partial
//  2) pool_reduce  -> pooled[8][768]
//  3) gamma_kernel -> gamma[8][768]
//  4) cvt_bf16 (W_out -> bf16)
//  5) pde_kernel: ONE WAVE per (b,c) channel, register-resident (R7, ~55us)
//  6) transpose_uv -> A [32768][1536] bf16
//  7) gemm_kernel (NEW): 1-WAVE workgroups, ZERO barriers. Wave owns a
//     128x96 C-tile (acc[8][6]); BK=32 single-buffered LDS 14KB. Per iter:
//     vmcnt(0) -> ds_read+48 MFMA -> lgkmcnt(0) -> stage next tile.
//     Latency hidden by TLP: 8 independent waves/CU (2/SIMD, balanced),
//     grid 2048 = exactly one generation. R8-proven swizzle/frags/epilogue.
//  Aliases: xT ~ A  (xT dead before A written); partial ~ uv (dead before pde)
// ---------------------------------------------------------------------------

typedef __attribute__((ext_vector_type(8))) short short8v;
typedef __attribute__((ext_vector_type(4))) float float4v;

static __device__ __forceinline__ unsigned short f2bf(float f) {
  unsigned u = __builtin_bit_cast(unsigned, f);
  u += 0x7FFFu + ((u >> 16) & 1u);   // round-to-nearest-even
  return (unsigned short)(u >> 16);
}

static __device__ __forceinline__ float softplusf(float x) {
  return (x > 20.0f) ? x : log1pf(expf(x));
}

// ---------------- transpose x [B,N,768] -> xT [B,768,N]  (+ pool partials) --
__global__ __launch_bounds__(256) void transpose_x_kernel(const float* __restrict__ x,
                                                          float* __restrict__ xT,
                                                          float* __restrict__ partial) {
  __shared__ float tile[64][65];
  __shared__ float red[4][64];
  const int c0 = blockIdx.x * 64;   // 12 tiles
  const int n0 = blockIdx.y * 64;   // 64 tiles
  const int b  = blockIdx.z;        // 8
  const int tl = threadIdx.x & 63;
  const int tw = threadIdx.x >> 6;  // 0..3
  const float* src = x + ((size_t)b * 4096 + n0) * 768 + c0;
  float s = 0.0f;
  #pragma unroll
  for (int j = 0; j < 16; ++j) {
    const int n = j * 4 + tw;
    const float val = src[(size_t)n * 768 + tl];
    tile[n][tl] = val;
    s += val;
  }
  red[tw][tl] = s;
  __syncthreads();
  if (tw == 0) {
    partial[((size_t)blockIdx.y * 8 + b) * 768 + c0 + tl] =
        red[0][tl] + red[1][tl] + red[2][tl] + red[3][tl];
  }
  float* dst = xT + ((size_t)b * 768 + c0) * 4096 + n0;
  #pragma unroll
  for (int j = 0; j < 16; ++j) {
    const int cc = j * 4 + tw;
    dst[(size_t)cc * 4096 + tl] = tile[tl][cc];
  }
}

__global__ void pool_reduce_kernel(const float* __restrict__ partial, float* __restrict__ pooled) {
  const int idx = blockIdx.x * 256 + threadIdx.x;   // 0..6143 = b*768+c
  float s = 0.0f;
  #pragma unroll
  for (int j = 0; j < 64; ++j) s += partial[(size_t)j * 6144 + idx];
  pooled[idx] = s * (1.0f / 4096.0f);
}

// ---------------- diffusion gate ----------------
__global__ void gamma_kernel(const float* __restrict__ pooled, const float* __restrict__ Wg,
                             const float* __restrict__ bg, float* __restrict__ gamma) {
  const int lane = threadIdx.x & 63;
  const int w = threadIdx.x >> 6;
  const int o = blockIdx.x * 4 + w;
  const int b = o / 768;
  const int j = o - b * 768;
  const float* pr = pooled + b * 768;
  const float* wr = Wg + (size_t)j * 768;
  float s = 0.0f;
  #pragma unroll
  for (int c = lane; c < 768; c += 64) s += pr[c] * wr[c];
  #pragma unroll
  for (int off = 32; off > 0; off >>= 1) s += __shfl_down(s, off);
  if (lane == 0) {
    float gin = s + bg[j];
    gamma[o] = fminf(softplusf(gin), 0.05f);
  }
}

// ---------------- W_out -> bf16 ----------------
__global__ void cvt_bf16_kernel(const float* __restrict__ src, unsigned short* __restrict__ dst, int n) {
  int i = blockIdx.x * 256 + threadIdx.x;
  if (i < n) dst[i] = f2bf(src[i]);
}

// ---------------- symplectic reaction-diffusion PDE (wave-per-channel) ------
__global__ __launch_bounds__(256, 2) void pde_kernel(
    const float* __restrict__ xT, const float* __restrict__ gamma,
    const float* __restrict__ alpha, const float* __restrict__ beta,
    const int* __restrict__ kp, unsigned short* __restrict__ uv) {
  const int w = threadIdx.x >> 6;
  const int lane = threadIdx.x & 63;
  const int cidx = blockIdx.x * 4 + w;
  const int b = cidx / 768;
  const int c = cidx - b * 768;
  const int lx = lane & 7;
  const int ly = lane >> 3;

  int ks = *kp; if (ks < 1) ks = 1;
  const float dt = 1.0f / (float)ks;
  const float hdt = 0.5f * dt;
  const float ae = 0.2f * tanhf(alpha[c]);
  const float be = fmaxf(softplusf(beta[c]), 1e-4f);
  const float g = gamma[b * 768 + c];
  const float c1n = -0.5f * dt * g;
  const float c2p = dt * g;

  const int laneL = (ly << 3) | ((lx + 7) & 7);
  const int laneR = (ly << 3) | ((lx + 1) & 7);
  const int laneU = (((ly + 7) & 7) << 3) | lx;
  const int laneD = (((ly + 1) & 7) << 3) | lx;

  float u[64], v[64];
  const float* xp = xT + ((size_t)b * 768 + c) * 4096;
  #pragma unroll
  for (int r = 0; r < 8; ++r) {
    const float4* src = (const float4*)(xp + (ly * 8 + r) * 64 + lx * 8);
    const float4 a0 = src[0], a1 = src[1];
    u[r * 8 + 0] = a0.x; u[r * 8 + 1] = a0.y; u[r * 8 + 2] = a0.z; u[r * 8 + 3] = a0.w;
    u[r * 8 + 4] = a1.x; u[r * 8 + 5] = a1.y; u[r * 8 + 6] = a1.z; u[r * 8 + 7] = a1.w;
  }
  #pragma unroll
  for (int i = 0; i < 64; ++i) v[i] = 0.0f;

  #define LAP_PHASE(F, G, COEF)                                               \
    {                                                                         \
      float lh[8], rh[8], uh[8], dh[8];                                       \
      _Pragma("unroll")                                                       \
      for (int r = 0; r < 8; ++r) {                                           \
        lh[r] = __shfl(F[r * 8 + 7], laneL);                                  \
        rh[r] = __shfl(F[r * 8 + 0], laneR);                                  \
        uh[r] = __shfl(F[56 + r], laneU);                                     \
        dh[r] = __shfl(F[r], laneD);                                          \
      }                                                                       \
      _Pragma("unroll")                                                       \
      for (int r = 0; r < 8; ++r) {                                           \
        _Pragma("unroll")                                                     \
        for (int j = 0; j < 8; ++j) {                                         \
          const float lf = (j == 0) ? lh[r] : F[r * 8 + j - 1];               \
          const float rt = (j == 7) ? rh[r] : F[r * 8 + j + 1];               \
          const float up = (r == 0) ? uh[j] : F[(r - 1) * 8 + j];             \
          const float dn = (r == 7) ? dh[j] : F[(r + 1) * 8 + j];             \
          const float lap = (lf + rt) + (up + dn) - 4.0f * F[r * 8 + j];      \
          G[r * 8 + j] = fmaf((COEF), lap, G[r * 8 + j]);                     \
        }                                                                     \
      }                                                                       \
    }

  for (int s = 0; s < ks; ++s) {
    #pragma unroll
    for (int i = 0; i < 64; ++i) {
      const float q = u[i] * u[i] + v[i] * v[i];
      const float rate = fminf(fmaxf(ae - be * q, -1.0f), 1.0f);
      const float t = hdt * rate;
      u[i] = fmaf(t, u[i], u[i]);
      v[i] = fmaf(t, v[i], v[i]);
    }
    LAP_PHASE(u, v, c1n)
    LAP_PHASE(v, u, c2p)
    LAP_PHASE(u, v, c1n)
    #pragma unroll
    for (int i = 0; i < 64; ++i) {
      const float q = u[i] * u[i] + v[i] * v[i];
      const float rate = fminf(fmaxf(ae - be * q, -1.0f), 1.0f);
      const float t = hdt * rate;
      u[i] = fmaf(t, u[i], u[i]);
      v[i] = fmaf(t, v[i], v[i]);
    }
  }
  #undef LAP_PHASE

  unsigned short* up_ = uv + ((size_t)b * 1536 + c) * 4096;
  unsigned short* vp_ = up_ + (size_t)768 * 4096;
  #pragma unroll
  for (int r = 0; r < 8; ++r) {
    const int off = (ly * 8 + r) * 64 + lx * 8;
    short8v us, vs;
    #pragma unroll
    for (int j = 0; j < 8; ++j) {
      us[j] = (short)f2bf(u[r * 8 + j]);
      vs[j] = (short)f2bf(v[r * 8 + j]);
    }
    *(short8v*)(up_ + off) = us;
    *(short8v*)(vp_ + off) = vs;
  }
}

// ---------------- transpose uv [8][1536][4096] -> A [32768][1536] ----------------
__global__ void transpose_uv_kernel(const unsigned short* __restrict__ src,
                                    unsigned short* __restrict__ dst) {
  __shared__ unsigned short tile[64][66];
  const int n0 = blockIdx.x * 64;
  const int k0 = blockIdx.y * 64;
  const int b = blockIdx.z;
  const int tx = threadIdx.x & 63;
  const int ty = threadIdx.x >> 6;
  const size_t sbase = ((size_t)b * 1536 + k0) * 4096 + n0;
  #pragma unroll
  for (int j = 0; j < 16; ++j) {
    const int k = ty + 4 * j;
    tile[k][tx] = src[sbase + (size_t)k * 4096 + tx];
  }
  __syncthreads();
  const size_t dbase = ((size_t)b * 4096 + n0) * 1536 + k0;
  #pragma unroll
  for (int j = 0; j < 16; ++j) {
    const int n = ty + 4 * j;
    dst[dbase + (size_t)n * 1536 + tx] = tile[tx][n];
  }
}

// ---------------- bf16 MFMA GEMM (1-wave blocks, no barriers) ---------------
// out = A @ W^T + x*D.  Wave owns 128x96 of C (acc[8][6]).  BK=32,
// single-buffered LDS: A 128x32 (8KB) + B 96x32 (6KB) = 14KB.
// Per K-iter: vmcnt(0) [tile ready] -> 14 ds_read_b128 + 48 MFMA (compiler
// interleaves) -> lgkmcnt(0) [reads retired] -> STAGE(next) [overwrite safe;
// latency hides under SIMD-mate's compute — 2 waves/SIMD, no barriers].
// Swizzle (64B rows, 4 x 16B slots): phys slot = logical ^ ((row>>1)&3)
//   staging src xor (lane>>3)&3 ; read xor (lane>>1)&3  (R8-proven, conf=0).
// Grid 2048 = 8 blocks/CU exactly one generation; XCD remap: the 8 n-blocks
// sharing an A-panel run consecutively on one XCD (1 HBM fetch + 7 L2 hits).
__global__ __launch_bounds__(64, 2) void gemm_kernel(
    const unsigned short* __restrict__ A,   // [32768][1536] bf16
    const unsigned short* __restrict__ Bt,  // [768][1536]  bf16 (W_out, B^T layout)
    const float* __restrict__ x,            // [32768][768]
    const float* __restrict__ Dv,           // [768]
    float* __restrict__ out) {              // [32768][768]
  __shared__ __align__(16) unsigned short Als[128 * 32];
  __shared__ __align__(16) unsigned short Bls[96 * 32];
  const int lane = threadIdx.x;   // 64-thread block = one wave

  // XCD-bijective remap: 2048 = 8 xcd x 32 mgrp x 8 nb.
  const int id = blockIdx.x;
  const int xcd = id & 7;
  const int seq = id >> 3;            // 0..255
  const int nb = seq & 7;             // 0..7
  const int mb = (seq >> 3) * 8 + xcd; // 0..255
  const int m0 = mb * 128;
  const int n0 = nb * 96;

  // staging: lane covers row (lane>>2) of a 16-row region, phys slot lane&3;
  // fetch global logical slot (lane&3)^((lane>>3)&3)
  const int src_col = (((lane & 3) ^ ((lane >> 3) & 3)) * 8);   // halfwords
  // read side: logical slot (lane>>4), row-phase xor (lane>>1)&3
  const int soff = ((lane >> 4) ^ ((lane >> 1) & 3)) * 8;       // halfwords

  float4v acc[8][6];
  #pragma unroll
  for (int a = 0; a < 8; ++a)
    #pragma unroll
    for (int bq = 0; bq < 6; ++bq)
      acc[a][bq] = (float4v){0.f, 0.f, 0.f, 0.f};

  // 14 global_load_lds (8 A + 6 B), 16B/lane, 16 rows per instruction
  #define STAGE(ktile)                                                        \
    _Pragma("unroll")                                                         \
    for (int i = 0; i < 8; ++i) {                                             \
      const int rb = i * 16;                                                  \
      __builtin_amdgcn_global_load_lds(                                       \
          (const __attribute__((address_space(1))) void*)(A + (size_t)(m0 + rb + (lane >> 2)) * 1536 + (ktile) * 32 + src_col), \
          (__attribute__((address_space(3))) void*)(&Als[rb * 32]), 16, 0, 0); \
    }                                                                         \
    _Pragma("unroll")                                                         \
    for (int i = 0; i < 6; ++i) {                                             \
      const int rb = i * 16;                                                  \
      __builtin_amdgcn_global_load_lds(                                       \
          (const __attribute__((address_space(1))) void*)(Bt + (size_t)(n0 + rb + (lane >> 2)) * 1536 + (ktile) * 32 + src_col), \
          (__attribute__((address_space(3))) void*)(&Bls[rb * 32]), 16, 0, 0); \
    }

  STAGE(0)
  for (int kt = 0; kt < 48; ++kt) {
    asm volatile("s_waitcnt vmcnt(0)" ::: "memory");   // wave-private: tile ready
    short8v bf[6];
    #pragma unroll
    for (int ni = 0; ni < 6; ++ni)
      bf[ni] = *(const short8v*)(&Bls[(ni * 16 + (lane & 15)) * 32 + soff]);
    #pragma unroll
    for (int mi = 0; mi < 8; ++mi) {
      const short8v af = *(const short8v*)(&Als[(mi * 16 + (lane & 15)) * 32 + soff]);
      #pragma unroll
      for (int ni = 0; ni < 6; ++ni)
        acc[mi][ni] = __builtin_amdgcn_mfma_f32_16x16x32_bf16(af, bf[ni], acc[mi][ni], 0, 0, 0);
    }
    if (kt + 1 < 48) {
      asm volatile("s_waitcnt lgkmcnt(0)" ::: "memory");  // ds_reads retired -> safe overwrite
      STAGE(kt + 1)
    }
  }
  #undef STAGE

  // epilogue: out = acc + x*D  (C/D layout: col=lane&15, row=(lane>>4)*4+r)
  #pragma unroll
  for (int ni = 0; ni < 6; ++ni) {
    const int col = n0 + ni * 16 + (lane & 15);
    const float dcol = Dv[col];
    #pragma unroll
    for (int mi = 0; mi < 8; ++mi) {
      #pragma unroll
      for (int r = 0; r < 4; ++r) {
        const int row = m0 + mi * 16 + (lane >> 4) * 4 + r;
        const size_t idx = (size_t)row * 768 + col;
        out[idx] = acc[mi][ni][r] + x[idx] * dcol;
      }
    }
  }
}

// ---------------------------------------------------------------------------
extern "C" void kernel_launch(void* const* d_in, const int* in_sizes, int n_in,
                              void* d_out, int out_size, void* d_ws, size_t ws_size,
                              hipStream_t stream) {
  const float* x     = (const float*)d_in[0];
  const float* Wg    = (const float*)d_in[1];
  const float* bg    = (const float*)d_in[2];
  const float* alpha = (const float*)d_in[3];
  const float* beta  = (const float*)d_in[4];
  const float* Wout  = (const float*)d_in[5];
  const float* Dv    = (const float*)d_in[6];
  const int*   kp    = (const int*)d_in[7];
  float* out = (float*)d_out;

  // workspace layout (~195 MiB)
  //   xT  aliases A   (xT dead before A is written by transpose_uv)
  //   partial aliases uv (partial consumed by pool_reduce before pde writes uv)
  char* ws = (char*)d_ws;
  unsigned short* A   = (unsigned short*)(ws);                 // 32768*1536*2   = 100663296
  float* xT           = (float*)(ws);                          // 8*768*4096*4   (alias A)
  unsigned short* uv  = (unsigned short*)(ws + 100663296);     // 8*1536*4096*2  = 100663296
  float* partial      = (float*)(ws + 100663296);              // 64*8*768*4     (alias uv)
  unsigned short* Wb  = (unsigned short*)(ws + 201326592);     // 768*1536*2     = 2359296
  float* pooled       = (float*)(ws + 203685888);              // 6144*4
  float* gam          = (float*)(ws + 203710464);              // 6144*4

  transpose_x_kernel<<<dim3(12, 64, 8), 256, 0, stream>>>(x, xT, partial);
  pool_reduce_kernel<<<24, 256, 0, stream>>>(partial, pooled);
  gamma_kernel<<<1536, 256, 0, stream>>>(pooled, Wg, bg, gam);
  cvt_bf16_kernel<<<(768 * 1536 + 255) / 256, 256, 0, stream>>>(Wout, Wb, 768 * 1536);
  pde_kernel<<<1536, 256, 0, stream>>>(xT, gam, alpha, beta, kp, uv);
  transpose_uv_kernel<<<dim3(64, 24, 8), 256, 0, stream>>>(uv, A);
  gemm_kernel<<<2048, 64, 0, stream>>>(A, Wb, x, Dv, out);
}

// Round 16
// 385.762 us; speedup vs baseline: 1.0344x; 1.0344x over previous
//
#include <hip/hip_runtime.h>
#include <hip/hip_bf16.h>
#include <math.h>

// ---------------------------------------------------------------------------
// RealSymplecticReactionDiffusion2D — round 14 kernel (resubmit, infra failure)
//  B=8, N=4096 (64x64), d=768, k_steps=4 (read from device)
// Stages:
//  1) pool_partial + pool_reduce -> pooled[8][768]  (R1-verified 2-stage)
//  2) gamma_kernel -> gamma[8][768]
//  3) cvt_bf16 (W_out -> bf16)
//  4) pde_kernel: wave-per-channel register-resident (R7-verified math).
//     Load phase: block's 4 waves = 4 CONSECUTIVE channels = one float4
//     of x -> coalesced 16B/lane direct x reads + LDS bounce. transpose_x
//     kernel ELIMINATED (-400MB fp32 traffic).
//  5) transpose_uv -> A [32768][1536] bf16
//  6) gemm_kernel: R7-EXACT (twice-verified 140us): 128x128 tile BK=64,
//     2-buf LDS, counted vmcnt(8), XOR swizzle (conflict=0), XCD remap.
//  Aliases: partial ~ uv (partial consumed by pool_reduce before pde writes uv)
// ---------------------------------------------------------------------------

typedef __attribute__((ext_vector_type(8))) short short8v;
typedef __attribute__((ext_vector_type(4))) float float4v;

static __device__ __forceinline__ unsigned short f2bf(float f) {
  unsigned u = __builtin_bit_cast(unsigned, f);
  u += 0x7FFFu + ((u >> 16) & 1u);   // round-to-nearest-even
  return (unsigned short)(u >> 16);
}

static __device__ __forceinline__ float softplusf(float x) {
  return (x > 20.0f) ? x : log1pf(expf(x));
}

// ---------------- pooling (deterministic, no atomics; R1-verified) ----------
__global__ void pool_partial_kernel(const float* __restrict__ x, float* __restrict__ partial) {
  // grid (3, 32, 8), block 256: partial[nchunk][b][c]
  const int c = blockIdx.x * 256 + threadIdx.x;     // 0..767
  const int n0 = blockIdx.y * 128;
  const int b = blockIdx.z;
  const float* xp = x + ((size_t)b * 4096 + n0) * 768 + c;
  float s = 0.0f;
  #pragma unroll 4
  for (int i = 0; i < 128; ++i) s += xp[(size_t)i * 768];
  partial[((size_t)blockIdx.y * 8 + b) * 768 + c] = s;
}

__global__ void pool_reduce_kernel(const float* __restrict__ partial, float* __restrict__ pooled) {
  const int idx = blockIdx.x * 256 + threadIdx.x;   // 0..6143 = b*768+c
  float s = 0.0f;
  #pragma unroll
  for (int j = 0; j < 32; ++j) s += partial[(size_t)j * 6144 + idx];
  pooled[idx] = s * (1.0f / 4096.0f);
}

// ---------------- diffusion gate ----------------
__global__ void gamma_kernel(const float* __restrict__ pooled, const float* __restrict__ Wg,
                             const float* __restrict__ bg, float* __restrict__ gamma) {
  const int lane = threadIdx.x & 63;
  const int w = threadIdx.x >> 6;
  const int o = blockIdx.x * 4 + w;
  const int b = o / 768;
  const int j = o - b * 768;
  const float* pr = pooled + b * 768;
  const float* wr = Wg + (size_t)j * 768;
  float s = 0.0f;
  #pragma unroll
  for (int c = lane; c < 768; c += 64) s += pr[c] * wr[c];
  #pragma unroll
  for (int off = 32; off > 0; off >>= 1) s += __shfl_down(s, off);
  if (lane == 0) {
    float gin = s + bg[j];
    gamma[o] = fminf(softplusf(gin), 0.05f);
  }
}

// ---------------- W_out -> bf16 ----------------
__global__ void cvt_bf16_kernel(const float* __restrict__ src, unsigned short* __restrict__ dst, int n) {
  int i = blockIdx.x * 256 + threadIdx.x;
  if (i < n) dst[i] = f2bf(src[i]);
}

// ---------------- symplectic reaction-diffusion PDE (wave-per-channel) ------
// One wave owns one (b,c) 64x64 grid; lanes = 8x8 grid, 8x8 register patch.
// Direct-x load phase. Block's 4 channels are CONSECUTIVE (c0..c0+3) =
// one float4 of x's last dim. 8 rounds: 256 threads load 512 cells x float4
// (coalesced 16B/lane) -> LDS (stride-5 cells within stride-323 rows,
// <=2-way banks) -> wave w takes component w. Math identical to R7-verified.
__global__ __launch_bounds__(256, 2) void pde_kernel(
    const float* __restrict__ x, const float* __restrict__ gamma,
    const float* __restrict__ alpha, const float* __restrict__ beta,
    const int* __restrict__ kp, unsigned short* __restrict__ uv) {
  __shared__ float stg[8 * 323 + 320];   // round staging, row stride 323
  const int w = threadIdx.x >> 6;          // wave 0..3 -> channel c0+w
  const int lane = threadIdx.x & 63;
  const int t = threadIdx.x;
  const int b = blockIdx.x / 192;          // 4 channels per block, 192 blocks/b
  const int c0 = (blockIdx.x - b * 192) * 4;
  const int c = c0 + w;
  const int lx = lane & 7;
  const int ly = lane >> 3;

  int ks = *kp; if (ks < 1) ks = 1;
  const float dt = 1.0f / (float)ks;
  const float hdt = 0.5f * dt;
  const float ae = 0.2f * tanhf(alpha[c]);
  const float be = fmaxf(softplusf(beta[c]), 1e-4f);
  const float g = gamma[b * 768 + c];
  const float c1n = -0.5f * dt * g;
  const float c2p = dt * g;

  const int laneL = (ly << 3) | ((lx + 7) & 7);
  const int laneR = (ly << 3) | ((lx + 1) & 7);
  const int laneU = (((ly + 7) & 7) << 3) | lx;
  const int laneD = (((ly + 1) & 7) << 3) | lx;

  float u[64], v[64];
  // load phase: round r covers grid rows {8q+r : q=0..7} (512 cells).
  // thread t: q=t>>5, two cells at cols 2*(t&31), 2*(t&31)+1 of row 8q+r.
  const float* xb = x + (size_t)b * 4096 * 768 + c0;
  #pragma unroll
  for (int r = 0; r < 8; ++r) {
    {
      const int q = t >> 5;
      const int col = (t & 31) * 2;
      const int n = (q * 8 + r) * 64 + col;
      const float4 fa = *(const float4*)(xb + (size_t)n * 768);
      const float4 fb = *(const float4*)(xb + (size_t)(n + 1) * 768);
      float* s0 = &stg[q * 323 + col * 5];
      s0[0] = fa.x; s0[1] = fa.y; s0[2] = fa.z; s0[3] = fa.w;
      s0[5] = fb.x; s0[6] = fb.y; s0[7] = fb.z; s0[8] = fb.w;
    }
    __syncthreads();
    #pragma unroll
    for (int j = 0; j < 8; ++j)
      u[r * 8 + j] = stg[ly * 323 + (lx * 8 + j) * 5 + w];
    __syncthreads();
  }
  #pragma unroll
  for (int i = 0; i < 64; ++i) v[i] = 0.0f;

  #define LAP_PHASE(F, G, COEF)                                               \
    {                                                                         \
      float lh[8], rh[8], uh[8], dh[8];                                       \
      _Pragma("unroll")                                                       \
      for (int r = 0; r < 8; ++r) {                                           \
        lh[r] = __shfl(F[r * 8 + 7], laneL);                                  \
        rh[r] = __shfl(F[r * 8 + 0], laneR);                                  \
        uh[r] = __shfl(F[56 + r], laneU);                                     \
        dh[r] = __shfl(F[r], laneD);                                          \
      }                                                                       \
      _Pragma("unroll")                                                       \
      for (int r = 0; r < 8; ++r) {                                           \
        _Pragma("unroll")                                                     \
        for (int j = 0; j < 8; ++j) {                                         \
          const float lf = (j == 0) ? lh[r] : F[r * 8 + j - 1];               \
          const float rt = (j == 7) ? rh[r] : F[r * 8 + j + 1];               \
          const float up = (r == 0) ? uh[j] : F[(r - 1) * 8 + j];             \
          const float dn = (r == 7) ? dh[j] : F[(r + 1) * 8 + j];             \
          const float lap = (lf + rt) + (up + dn) - 4.0f * F[r * 8 + j];      \
          G[r * 8 + j] = fmaf((COEF), lap, G[r * 8 + j]);                     \
        }                                                                     \
      }                                                                       \
    }

  for (int s = 0; s < ks; ++s) {
    #pragma unroll
    for (int i = 0; i < 64; ++i) {
      const float q = u[i] * u[i] + v[i] * v[i];
      const float rate = fminf(fmaxf(ae - be * q, -1.0f), 1.0f);
      const float tt = hdt * rate;
      u[i] = fmaf(tt, u[i], u[i]);
      v[i] = fmaf(tt, v[i], v[i]);
    }
    LAP_PHASE(u, v, c1n)
    LAP_PHASE(v, u, c2p)
    LAP_PHASE(u, v, c1n)
    #pragma unroll
    for (int i = 0; i < 64; ++i) {
      const float q = u[i] * u[i] + v[i] * v[i];
      const float rate = fminf(fmaxf(ae - be * q, -1.0f), 1.0f);
      const float tt = hdt * rate;
      u[i] = fmaf(tt, u[i], u[i]);
      v[i] = fmaf(tt, v[i], v[i]);
    }
  }
  #undef LAP_PHASE

  // write out channel-major bf16: uv[b][c][n] = u, uv[b][768+c][n] = v
  unsigned short* up_ = uv + ((size_t)b * 1536 + c) * 4096;
  unsigned short* vp_ = up_ + (size_t)768 * 4096;
  #pragma unroll
  for (int r = 0; r < 8; ++r) {
    const int off = (ly * 8 + r) * 64 + lx * 8;
    short8v us, vs;
    #pragma unroll
    for (int j = 0; j < 8; ++j) {
      us[j] = (short)f2bf(u[r * 8 + j]);
      vs[j] = (short)f2bf(v[r * 8 + j]);
    }
    *(short8v*)(up_ + off) = us;
    *(short8v*)(vp_ + off) = vs;
  }
}

// ---------------- transpose uv [8][1536][4096] -> A [32768][1536] ----------------
__global__ void transpose_uv_kernel(const unsigned short* __restrict__ src,
                                    unsigned short* __restrict__ dst) {
  __shared__ unsigned short tile[64][66];
  const int n0 = blockIdx.x * 64;
  const int k0 = blockIdx.y * 64;
  const int b = blockIdx.z;
  const int tx = threadIdx.x & 63;
  const int ty = threadIdx.x >> 6;
  const size_t sbase = ((size_t)b * 1536 + k0) * 4096 + n0;
  #pragma unroll
  for (int j = 0; j < 16; ++j) {
    const int k = ty + 4 * j;
    tile[k][tx] = src[sbase + (size_t)k * 4096 + tx];
  }
  __syncthreads();
  const size_t dbase = ((size_t)b * 4096 + n0) * 1536 + k0;
  #pragma unroll
  for (int j = 0; j < 16; ++j) {
    const int n = ty + 4 * j;
    dst[dbase + (size_t)n * 1536 + tx] = tile[tx][n];
  }
}

// ---------------- bf16 MFMA GEMM (R7-EXACT, twice-verified ~140us) ----------
__global__ __launch_bounds__(256) void gemm_kernel(
    const unsigned short* __restrict__ A,   // [32768][1536] bf16
    const unsigned short* __restrict__ Bt,  // [768][1536]  bf16 (W_out, B^T layout)
    const float* __restrict__ x,            // [32768][768]
    const float* __restrict__ Dv,           // [768]
    float* __restrict__ out) {              // [32768][768]
  __shared__ __align__(16) unsigned short Als[2][128 * 64];
  __shared__ __align__(16) unsigned short Bls[2][128 * 64];
  const int tid = threadIdx.x;
  const int lane = tid & 63;
  const int w = tid >> 6;       // wave 0..3
  const int wr = w >> 1;        // wave row (2x2 waves, each 64x64 of C)
  const int wc = w & 1;

  // XCD-chunked remap: id -> (m-block, n-block). 1536 blocks, 8 XCDs.
  const int id = blockIdx.x;
  const int xcd = id & 7;
  const int seq = id >> 3;          // 0..191
  const int nb = seq % 6;
  const int mb = (seq / 6) * 8 + xcd;
  const int m0 = mb * 128;
  const int n0 = nb * 128;

  // staging-side swizzle: lane covers row (lane>>3), phys slot (lane&7);
  // load global logical slot (lane&7)^(lane>>3)
  const int src_col = (((lane & 7) ^ (lane >> 3)) * 8);   // halfwords
  // read-side: quarter-wave q, row-low bits rlow
  const int q = lane >> 4;
  const int rlow = lane & 7;

  float4v acc[4][4];
  #pragma unroll
  for (int a = 0; a < 4; ++a)
    #pragma unroll
    for (int bq = 0; bq < 4; ++bq)
      acc[a][bq] = (float4v){0.f, 0.f, 0.f, 0.f};

  // per-wave: 8 global_load_lds (4 A + 4 B), 16B each
  #define STAGE(bufi, kbase)                                                  \
    _Pragma("unroll")                                                         \
    for (int i = 0; i < 4; ++i) {                                             \
      const int rowblk = (w * 4 + i) * 8;                                     \
      const int row = rowblk + (lane >> 3);                                   \
      const int kk = (kbase) + src_col;                                       \
      __builtin_amdgcn_global_load_lds(                                       \
          (const __attribute__((address_space(1))) void*)(A + (size_t)(m0 + row) * 1536 + kk), \
          (__attribute__((address_space(3))) void*)(&Als[bufi][rowblk * 64]), 16, 0, 0); \
      __builtin_amdgcn_global_load_lds(                                       \
          (const __attribute__((address_space(1))) void*)(Bt + (size_t)(n0 + row) * 1536 + kk), \
          (__attribute__((address_space(3))) void*)(&Bls[bufi][rowblk * 64]), 16, 0, 0); \
    }

  STAGE(0, 0)
  int cur = 0;
  for (int kt = 0; kt < 24; ++kt) {
    // bar1: all waves' reads of buf[cur^1] retired -> safe to re-stage
    __builtin_amdgcn_s_barrier();
    if (kt < 23) {
      STAGE(cur ^ 1, (kt + 1) * 64)
      asm volatile("s_waitcnt vmcnt(8)" ::: "memory");   // wait prev 8, keep new 8 in flight
    } else {
      asm volatile("s_waitcnt vmcnt(0)" ::: "memory");   // last tile: drain
    }
    // bar2: every wave has its current buffer's loads complete
    __builtin_amdgcn_s_barrier();
    __builtin_amdgcn_sched_barrier(0);
    #pragma unroll
    for (int ksub = 0; ksub < 2; ++ksub) {
      const int soff = ((ksub * 4 + q) ^ rlow) * 8;    // swizzled 16B slot (halfwords)
      short8v af[4], bf[4];
      #pragma unroll
      for (int mi = 0; mi < 4; ++mi)
        af[mi] = *(const short8v*)(&Als[cur][(wr * 64 + mi * 16 + (lane & 15)) * 64 + soff]);
      #pragma unroll
      for (int ni = 0; ni < 4; ++ni)
        bf[ni] = *(const short8v*)(&Bls[cur][(wc * 64 + ni * 16 + (lane & 15)) * 64 + soff]);
      #pragma unroll
      for (int mi = 0; mi < 4; ++mi)
        #pragma unroll
        for (int ni = 0; ni < 4; ++ni)
          acc[mi][ni] = __builtin_amdgcn_mfma_f32_16x16x32_bf16(af[mi], bf[ni], acc[mi][ni], 0, 0, 0);
    }
    cur ^= 1;
  }
  #undef STAGE

  // epilogue: out = acc + x*D  (C/D layout: col=lane&15, row=(lane>>4)*4+r)
  #pragma unroll
  for (int ni = 0; ni < 4; ++ni) {
    const int col = n0 + wc * 64 + ni * 16 + (lane & 15);
    const float dcol = Dv[col];
    #pragma unroll
    for (int mi = 0; mi < 4; ++mi) {
      #pragma unroll
      for (int r = 0; r < 4; ++r) {
        const int row = m0 + wr * 64 + mi * 16 + (lane >> 4) * 4 + r;
        const size_t idx = (size_t)row * 768 + col;
        out[idx] = acc[mi][ni][r] + x[idx] * dcol;
      }
    }
  }
}

// ---------------------------------------------------------------------------
extern "C" void kernel_launch(void* const* d_in, const int* in_sizes, int n_in,
                              void* d_out, int out_size, void* d_ws, size_t ws_size,
                              hipStream_t stream) {
  const float* x     = (const float*)d_in[0];
  const float* Wg    = (const float*)d_in[1];
  const float* bg    = (const float*)d_in[2];
  const float* alpha = (const float*)d_in[3];
  const float* beta  = (const float*)d_in[4];
  const float* Wout  = (const float*)d_in[5];
  const float* Dv    = (const float*)d_in[6];
  const int*   kp    = (const int*)d_in[7];
  float* out = (float*)d_out;

  // workspace layout (~195 MiB)
  //   partial aliases uv (partial consumed by pool_reduce before pde writes uv)
  char* ws = (char*)d_ws;
  unsigned short* A   = (unsigned short*)(ws);                 // 32768*1536*2   = 100663296
  unsigned short* uv  = (unsigned short*)(ws + 100663296);     // 8*1536*4096*2  = 100663296
  float* partial      = (float*)(ws + 100663296);              // 32*8*768*4     (alias uv)
  unsigned short* Wb  = (unsigned short*)(ws + 201326592);     // 768*1536*2     = 2359296
  float* pooled       = (float*)(ws + 203685888);              // 6144*4
  float* gam          = (float*)(ws + 203710464);              // 6144*4

  pool_partial_kernel<<<dim3(3, 32, 8), 256, 0, stream>>>(x, partial);
  pool_reduce_kernel<<<24, 256, 0, stream>>>(partial, pooled);
  gamma_kernel<<<1536, 256, 0, stream>>>(pooled, Wg, bg, gam);
  cvt_bf16_kernel<<<(768 * 1536 + 255) / 256, 256, 0, stream>>>(Wout, Wb, 768 * 1536);
  pde_kernel<<<1536, 256, 0, stream>>>(x, gam, alpha, beta, kp, uv);
  transpose_uv_kernel<<<dim3(64, 24, 8), 256, 0, stream>>>(uv, A);
  gemm_kernel<<<1536, 256, 0, stream>>>(A, Wb, x, Dv, out);
}

// Round 17
// 331.522 us; speedup vs baseline: 1.2037x; 1.1636x over previous
//
#include <hip/hip_runtime.h>
#include <hip/hip_bf16.h>
#include <math.h>

// ---------------------------------------------------------------------------
// RealSymplecticReactionDiffusion2D — round 16
//  B=8, N=4096 (64x64), d=768, k_steps=4 (read from device)
// Stages:
//  1) transpose_x (FUSED pool partials) -> xT + partial   (R5-verified)
//  2) pool_reduce -> pooled[8][768]                       (R5-verified)
//  3) gamma_kernel -> gamma[8][768]
//  4) cvt_bf16 (W_out -> bf16)
//  5) pde_kernel: 512 thr = 8 waves = 8 CONSECUTIVE channels; R7-verified
//     register-resident math reading xT; NEW output: LDS bounce (64KB,
//     u then v) -> writes A_blk[b][g][n][8ch] DIRECTLY (coalesced 16B/thr).
//     transpose_uv ELIMINATED (-200MB bf16 traffic).
//  6) gemm_kernel: R7 skeleton (2-buf BK=64, vmcnt(8), XCD remap); A staged
//     from A_blk ([8g][128n][16B] LDS tile, frag = b128 at (ksub*4+q)*1024,
//     bank-checked conflict-free); B path/swizzle R7-exact.
//  Aliases: partial ~ A_blk (partial dead after pool_reduce, before pde).
// ---------------------------------------------------------------------------

typedef __attribute__((ext_vector_type(8))) short short8v;
typedef __attribute__((ext_vector_type(4))) short short4v;
typedef __attribute__((ext_vector_type(4))) float float4v;

static __device__ __forceinline__ unsigned short f2bf(float f) {
  unsigned u = __builtin_bit_cast(unsigned, f);
  u += 0x7FFFu + ((u >> 16) & 1u);   // round-to-nearest-even
  return (unsigned short)(u >> 16);
}

static __device__ __forceinline__ float softplusf(float x) {
  return (x > 20.0f) ? x : log1pf(expf(x));
}

// ---------------- transpose x [B,N,768] -> xT [B,768,N]  (+ pool partials) --
__global__ __launch_bounds__(256) void transpose_x_kernel(const float* __restrict__ x,
                                                          float* __restrict__ xT,
                                                          float* __restrict__ partial) {
  __shared__ float tile[64][65];
  __shared__ float red[4][64];
  const int c0 = blockIdx.x * 64;   // 12 tiles
  const int n0 = blockIdx.y * 64;   // 64 tiles
  const int b  = blockIdx.z;        // 8
  const int tl = threadIdx.x & 63;
  const int tw = threadIdx.x >> 6;  // 0..3
  const float* src = x + ((size_t)b * 4096 + n0) * 768 + c0;
  float s = 0.0f;
  #pragma unroll
  for (int j = 0; j < 16; ++j) {
    const int n = j * 4 + tw;
    const float val = src[(size_t)n * 768 + tl];
    tile[n][tl] = val;
    s += val;
  }
  red[tw][tl] = s;
  __syncthreads();
  // partial[n-chunk][b][c] ; n-chunk = blockIdx.y (64 chunks)
  if (tw == 0) {
    partial[((size_t)blockIdx.y * 8 + b) * 768 + c0 + tl] =
        red[0][tl] + red[1][tl] + red[2][tl] + red[3][tl];
  }
  float* dst = xT + ((size_t)b * 768 + c0) * 4096 + n0;
  #pragma unroll
  for (int j = 0; j < 16; ++j) {
    const int cc = j * 4 + tw;
    dst[(size_t)cc * 4096 + tl] = tile[tl][cc];
  }
}

__global__ void pool_reduce_kernel(const float* __restrict__ partial, float* __restrict__ pooled) {
  const int idx = blockIdx.x * 256 + threadIdx.x;   // 0..6143 = b*768+c
  float s = 0.0f;
  #pragma unroll
  for (int j = 0; j < 64; ++j) s += partial[(size_t)j * 6144 + idx];
  pooled[idx] = s * (1.0f / 4096.0f);
}

// ---------------- diffusion gate ----------------
__global__ void gamma_kernel(const float* __restrict__ pooled, const float* __restrict__ Wg,
                             const float* __restrict__ bg, float* __restrict__ gamma) {
  const int lane = threadIdx.x & 63;
  const int w = threadIdx.x >> 6;
  const int o = blockIdx.x * 4 + w;
  const int b = o / 768;
  const int j = o - b * 768;
  const float* pr = pooled + b * 768;
  const float* wr = Wg + (size_t)j * 768;
  float s = 0.0f;
  #pragma unroll
  for (int c = lane; c < 768; c += 64) s += pr[c] * wr[c];
  #pragma unroll
  for (int off = 32; off > 0; off >>= 1) s += __shfl_down(s, off);
  if (lane == 0) {
    float gin = s + bg[j];
    gamma[o] = fminf(softplusf(gin), 0.05f);
  }
}

// ---------------- W_out -> bf16 ----------------
__global__ void cvt_bf16_kernel(const float* __restrict__ src, unsigned short* __restrict__ dst, int n) {
  int i = blockIdx.x * 256 + threadIdx.x;
  if (i < n) dst[i] = f2bf(src[i]);
}

// ---------------- symplectic reaction-diffusion PDE (wave-per-channel) ------
// 8 waves = 8 consecutive channels (cg*8 .. cg*8+7). Per wave: R7-verified
// register-resident 64x64 evolution reading xT coalesced. Output: LDS bounce
// fld[8ch][4096n] (64KB, u then v) -> A_blk[b][g][n][8ch] coalesced.
__global__ __launch_bounds__(512, 1) void pde_kernel(
    const float* __restrict__ xT, const float* __restrict__ gamma,
    const float* __restrict__ alpha, const float* __restrict__ beta,
    const int* __restrict__ kp, unsigned short* __restrict__ Ablk) {
  __shared__ __align__(16) unsigned short fld[8][4096];   // 64KB, reused u->v
  const int w = threadIdx.x >> 6;          // wave 0..7 -> channel cg*8+w
  const int lane = threadIdx.x & 63;
  const int t = threadIdx.x;
  const int b = blockIdx.x / 96;           // 768 blocks = 8 b x 96 cgroups
  const int cg = blockIdx.x - b * 96;
  const int c = cg * 8 + w;
  const int lx = lane & 7;
  const int ly = lane >> 3;

  int ks = *kp; if (ks < 1) ks = 1;
  const float dt = 1.0f / (float)ks;
  const float hdt = 0.5f * dt;
  const float ae = 0.2f * tanhf(alpha[c]);
  const float be = fmaxf(softplusf(beta[c]), 1e-4f);
  const float g = gamma[b * 768 + c];
  const float c1n = -0.5f * dt * g;
  const float c2p = dt * g;

  const int laneL = (ly << 3) | ((lx + 7) & 7);
  const int laneR = (ly << 3) | ((lx + 1) & 7);
  const int laneU = (((ly + 7) & 7) << 3) | lx;
  const int laneD = (((ly + 1) & 7) << 3) | lx;

  float u[64], v[64];
  const float* xp = xT + ((size_t)b * 768 + c) * 4096;
  #pragma unroll
  for (int r = 0; r < 8; ++r) {
    const float4* src = (const float4*)(xp + (ly * 8 + r) * 64 + lx * 8);
    const float4 a0 = src[0], a1 = src[1];
    u[r * 8 + 0] = a0.x; u[r * 8 + 1] = a0.y; u[r * 8 + 2] = a0.z; u[r * 8 + 3] = a0.w;
    u[r * 8 + 4] = a1.x; u[r * 8 + 5] = a1.y; u[r * 8 + 6] = a1.z; u[r * 8 + 7] = a1.w;
  }
  #pragma unroll
  for (int i = 0; i < 64; ++i) v[i] = 0.0f;

  #define LAP_PHASE(F, G, COEF)                                               \
    {                                                                         \
      float lh[8], rh[8], uh[8], dh[8];                                       \
      _Pragma("unroll")                                                       \
      for (int r = 0; r < 8; ++r) {                                           \
        lh[r] = __shfl(F[r * 8 + 7], laneL);                                  \
        rh[r] = __shfl(F[r * 8 + 0], laneR);                                  \
        uh[r] = __shfl(F[56 + r], laneU);                                     \
        dh[r] = __shfl(F[r], laneD);                                          \
      }                                                                       \
      _Pragma("unroll")                                                       \
      for (int r = 0; r < 8; ++r) {                                           \
        _Pragma("unroll")                                                     \
        for (int j = 0; j < 8; ++j) {                                         \
          const float lf = (j == 0) ? lh[r] : F[r * 8 + j - 1];               \
          const float rt = (j == 7) ? rh[r] : F[r * 8 + j + 1];               \
          const float up = (r == 0) ? uh[j] : F[(r - 1) * 8 + j];             \
          const float dn = (r == 7) ? dh[j] : F[(r + 1) * 8 + j];             \
          const float lap = (lf + rt) + (up + dn) - 4.0f * F[r * 8 + j];      \
          G[r * 8 + j] = fmaf((COEF), lap, G[r * 8 + j]);                     \
        }                                                                     \
      }                                                                       \
    }

  for (int s = 0; s < ks; ++s) {
    #pragma unroll
    for (int i = 0; i < 64; ++i) {
      const float q = u[i] * u[i] + v[i] * v[i];
      const float rate = fminf(fmaxf(ae - be * q, -1.0f), 1.0f);
      const float tt = hdt * rate;
      u[i] = fmaf(tt, u[i], u[i]);
      v[i] = fmaf(tt, v[i], v[i]);
    }
    LAP_PHASE(u, v, c1n)
    LAP_PHASE(v, u, c2p)
    LAP_PHASE(u, v, c1n)
    #pragma unroll
    for (int i = 0; i < 64; ++i) {
      const float q = u[i] * u[i] + v[i] * v[i];
      const float rate = fminf(fmaxf(ae - be * q, -1.0f), 1.0f);
      const float tt = hdt * rate;
      u[i] = fmaf(tt, u[i], u[i]);
      v[i] = fmaf(tt, v[i], v[i]);
    }
  }
  #undef LAP_PHASE

  // ---- output: LDS bounce, then coalesced A_blk write. u -> groups 0..95,
  // v -> groups 96..191. A_blk elem offset: (b*192+g)*32768 + n*8 + ch.
  #define DUMP(F, gbase)                                                      \
    {                                                                         \
      _Pragma("unroll")                                                       \
      for (int r = 0; r < 8; ++r) {                                           \
        short8v o;                                                            \
        _Pragma("unroll")                                                     \
        for (int j = 0; j < 8; ++j) o[j] = (short)f2bf(F[r * 8 + j]);         \
        *(short8v*)(&fld[w][(ly * 8 + r) * 64 + lx * 8]) = o;                 \
      }                                                                       \
      __syncthreads();                                                        \
      unsigned short* ab = Ablk + ((size_t)(b * 192 + (gbase) + cg)) * 32768; \
      _Pragma("unroll")                                                       \
      for (int rr = 0; rr < 2; ++rr) {                                        \
        const int n0 = (rr * 512 + t) * 4;                                    \
        short4v sv[8];                                                        \
        _Pragma("unroll")                                                     \
        for (int ch = 0; ch < 8; ++ch) sv[ch] = *(const short4v*)(&fld[ch][n0]); \
        _Pragma("unroll")                                                     \
        for (int dn = 0; dn < 4; ++dn) {                                      \
          short8v o;                                                          \
          _Pragma("unroll")                                                   \
          for (int ch = 0; ch < 8; ++ch) o[ch] = sv[ch][dn];                  \
          *(short8v*)(ab + (size_t)(n0 + dn) * 8) = o;                        \
        }                                                                     \
      }                                                                       \
      __syncthreads();                                                        \
    }

  DUMP(u, 0)
  DUMP(v, 96)
  #undef DUMP
}

// ---------------- bf16 MFMA GEMM (R7 skeleton, A from A_blk) ----------------
// out = A @ W^T + x*D.  128x128 tile, BK=64, 2-buf LDS, vmcnt(8), XCD remap.
// A LDS tile [8 g][128 n][8 ch] (16B units), staged 1KB-contiguous from
// A_blk; frag read = b128 at (ksub*4+q)*1024 + row*8 (conflict-free:
// 16 n x 4 g spread = minimum bank cycles). B path swizzled, R7-exact.
__global__ __launch_bounds__(256) void gemm_kernel(
    const unsigned short* __restrict__ Ablk, // [8][192][4096][8] bf16
    const unsigned short* __restrict__ Bt,   // [768][1536]  bf16 (W_out)
    const float* __restrict__ x,             // [32768][768]
    const float* __restrict__ Dv,            // [768]
    float* __restrict__ out) {               // [32768][768]
  __shared__ __align__(16) unsigned short Als[2][128 * 64];
  __shared__ __align__(16) unsigned short Bls[2][128 * 64];
  const int tid = threadIdx.x;
  const int lane = tid & 63;
  const int w = tid >> 6;       // wave 0..3
  const int wr = w >> 1;        // wave row (2x2 waves, each 64x64 of C)
  const int wc = w & 1;

  // XCD-chunked remap: id -> (m-block, n-block). 1536 blocks, 8 XCDs.
  const int id = blockIdx.x;
  const int xcd = id & 7;
  const int seq = id >> 3;          // 0..191
  const int nb = seq % 6;
  const int mb = (seq / 6) * 8 + xcd;
  const int m0 = mb * 128;
  const int n0 = nb * 128;
  const int bb = m0 >> 12;          // batch of this m-panel (128 | 4096)
  const int nb0 = m0 & 4095;        // n offset within batch

  // B staging swizzle (R7): load global logical slot (lane&7)^(lane>>3)
  const int src_col = (((lane & 7) ^ (lane >> 3)) * 8);   // halfwords
  // read-side: quarter-wave q, row-low bits rlow (B only)
  const int q = lane >> 4;
  const int rlow = lane & 7;

  float4v acc[4][4];
  #pragma unroll
  for (int a = 0; a < 4; ++a)
    #pragma unroll
    for (int bq = 0; bq < 4; ++bq)
      acc[a][bq] = (float4v){0.f, 0.f, 0.f, 0.f};

  // per-wave: 4 A + 4 B global_load_lds, 16B each (vmcnt budget 8, as R7)
  #define STAGE(bufi, kt)                                                     \
    _Pragma("unroll")                                                         \
    for (int i = 0; i < 4; ++i) {                                             \
      const int idx = w * 4 + i;            /* 0..15 */                       \
      const int g_off = idx >> 1;           /* 0..7  */                       \
      const int half = idx & 1;                                               \
      __builtin_amdgcn_global_load_lds(                                       \
          (const __attribute__((address_space(1))) void*)(Ablk + ((size_t)(bb * 192 + (kt) * 8 + g_off)) * 32768 + (size_t)(nb0 + half * 64 + lane) * 8), \
          (__attribute__((address_space(3))) void*)(&Als[bufi][g_off * 1024 + half * 512]), 16, 0, 0); \
      const int rowblk = idx * 8;                                             \
      const int row = rowblk + (lane >> 3);                                   \
      __builtin_amdgcn_global_load_lds(                                       \
          (const __attribute__((address_space(1))) void*)(Bt + (size_t)(n0 + row) * 1536 + (kt) * 64 + src_col), \
          (__attribute__((address_space(3))) void*)(&Bls[bufi][rowblk * 64]), 16, 0, 0); \
    }

  STAGE(0, 0)
  int cur = 0;
  for (int kt = 0; kt < 24; ++kt) {
    // bar1: all waves' reads of buf[cur^1] retired -> safe to re-stage
    __builtin_amdgcn_s_barrier();
    if (kt < 23) {
      STAGE(cur ^ 1, kt + 1)
      asm volatile("s_waitcnt vmcnt(8)" ::: "memory");   // wait prev 8, keep new 8 in flight
    } else {
      asm volatile("s_waitcnt vmcnt(0)" ::: "memory");   // last tile: drain
    }
    // bar2: every wave has its current buffer's loads complete
    __builtin_amdgcn_s_barrier();
    __builtin_amdgcn_sched_barrier(0);
    #pragma unroll
    for (int ksub = 0; ksub < 2; ++ksub) {
      const int soff = ((ksub * 4 + q) ^ rlow) * 8;    // B swizzled slot
      const int ga = (ksub * 4 + q) * 1024;            // A group base (halfwords)
      short8v af[4], bf[4];
      #pragma unroll
      for (int mi = 0; mi < 4; ++mi)
        af[mi] = *(const short8v*)(&Als[cur][ga + (wr * 64 + mi * 16 + (lane & 15)) * 8]);
      #pragma unroll
      for (int ni = 0; ni < 4; ++ni)
        bf[ni] = *(const short8v*)(&Bls[cur][(wc * 64 + ni * 16 + (lane & 15)) * 64 + soff]);
      #pragma unroll
      for (int mi = 0; mi < 4; ++mi)
        #pragma unroll
        for (int ni = 0; ni < 4; ++ni)
          acc[mi][ni] = __builtin_amdgcn_mfma_f32_16x16x32_bf16(af[mi], bf[ni], acc[mi][ni], 0, 0, 0);
    }
    cur ^= 1;
  }
  #undef STAGE

  // epilogue: out = acc + x*D  (C/D layout: col=lane&15, row=(lane>>4)*4+r)
  #pragma unroll
  for (int ni = 0; ni < 4; ++ni) {
    const int col = n0 + wc * 64 + ni * 16 + (lane & 15);
    const float dcol = Dv[col];
    #pragma unroll
    for (int mi = 0; mi < 4; ++mi) {
      #pragma unroll
      for (int r = 0; r < 4; ++r) {
        const int row = m0 + wr * 64 + mi * 16 + (lane >> 4) * 4 + r;
        const size_t idx = (size_t)row * 768 + col;
        out[idx] = acc[mi][ni][r] + x[idx] * dcol;
      }
    }
  }
}

// ---------------------------------------------------------------------------
extern "C" void kernel_launch(void* const* d_in, const int* in_sizes, int n_in,
                              void* d_out, int out_size, void* d_ws, size_t ws_size,
                              hipStream_t stream) {
  const float* x     = (const float*)d_in[0];
  const float* Wg    = (const float*)d_in[1];
  const float* bg    = (const float*)d_in[2];
  const float* alpha = (const float*)d_in[3];
  const float* beta  = (const float*)d_in[4];
  const float* Wout  = (const float*)d_in[5];
  const float* Dv    = (const float*)d_in[6];
  const int*   kp    = (const int*)d_in[7];
  float* out = (float*)d_out;

  // workspace layout (proven 203735040-byte footprint)
  //   partial aliases A_blk (partial dead after pool_reduce, before pde)
  char* ws = (char*)d_ws;
  unsigned short* Ablk = (unsigned short*)(ws);                // 8*192*4096*8*2 = 100663296
  float* partial       = (float*)(ws);                         // 64*8*768*4 (alias Ablk)
  float* xT            = (float*)(ws + 100663296);             // 8*768*4096*4   = 100663296
  unsigned short* Wb   = (unsigned short*)(ws + 201326592);    // 768*1536*2     = 2359296
  float* pooled        = (float*)(ws + 203685888);             // 6144*4
  float* gam           = (float*)(ws + 203710464);             // 6144*4

  transpose_x_kernel<<<dim3(12, 64, 8), 256, 0, stream>>>(x, xT, partial);
  pool_reduce_kernel<<<24, 256, 0, stream>>>(partial, pooled);
  gamma_kernel<<<1536, 256, 0, stream>>>(pooled, Wg, bg, gam);
  cvt_bf16_kernel<<<(768 * 1536 + 255) / 256, 256, 0, stream>>>(Wout, Wb, 768 * 1536);
  pde_kernel<<<768, 512, 0, stream>>>(xT, gam, alpha, beta, kp, Ablk);
  gemm_kernel<<<1536, 256, 0, stream>>>(Ablk, Wb, x, Dv, out);
}

// Round 18
// 310.512 us; speedup vs baseline: 1.2851x; 1.0677x over previous
//
#include <hip/hip_runtime.h>
#include <hip/hip_bf16.h>
#include <math.h>

// ---------------------------------------------------------------------------
// RealSymplecticReactionDiffusion2D — round 17
//  = the 310.7us-verified R8 structure, ONE isolated change:
//    pde __launch_bounds__ (256,2) -> (256,1)  [free the register allocator:
//    u[64]+v[64] need 128 floats; VGPR_Count=108 showed AGPR banking+bounce]
// Stages:
//  1) transpose_x (FUSED column-sum partials for mean-pool) -> xT + partial
//  2) pool_reduce  -> pooled[8][768]
//  3) gamma_kernel -> gamma[8][768]
//  4) cvt_bf16 (W_out -> bf16)
//  5) pde_kernel: ONE WAVE per (b,c) channel — 8x8 lane grid, 8x8 register
//     patch per lane; halo via 32 shfls; no LDS/barriers.
//  6) transpose_uv -> A [32768][1536] bf16
//  7) gemm_kernel: 128x128 tile BK=64, 2-buf LDS, counted vmcnt(8),
//     XOR swizzle (conflict=0), XCD remap  (~140us, thrice-verified)
//  Aliases: xT ~ A  (xT dead before A written); partial ~ uv (dead before pde)
// ---------------------------------------------------------------------------

typedef __attribute__((ext_vector_type(8))) short short8v;
typedef __attribute__((ext_vector_type(4))) float float4v;

static __device__ __forceinline__ unsigned short f2bf(float f) {
  unsigned u = __builtin_bit_cast(unsigned, f);
  u += 0x7FFFu + ((u >> 16) & 1u);   // round-to-nearest-even
  return (unsigned short)(u >> 16);
}

static __device__ __forceinline__ float softplusf(float x) {
  return (x > 20.0f) ? x : log1pf(expf(x));
}

// ---------------- transpose x [B,N,768] -> xT [B,768,N]  (+ pool partials) --
__global__ __launch_bounds__(256) void transpose_x_kernel(const float* __restrict__ x,
                                                          float* __restrict__ xT,
                                                          float* __restrict__ partial) {
  __shared__ float tile[64][65];
  __shared__ float red[4][64];
  const int c0 = blockIdx.x * 64;   // 12 tiles
  const int n0 = blockIdx.y * 64;   // 64 tiles
  const int b  = blockIdx.z;        // 8
  const int tl = threadIdx.x & 63;
  const int tw = threadIdx.x >> 6;  // 0..3
  const float* src = x + ((size_t)b * 4096 + n0) * 768 + c0;
  float s = 0.0f;
  #pragma unroll
  for (int j = 0; j < 16; ++j) {
    const int n = j * 4 + tw;
    const float val = src[(size_t)n * 768 + tl];
    tile[n][tl] = val;
    s += val;
  }
  red[tw][tl] = s;
  __syncthreads();
  // partial[n-chunk][b][c] ; n-chunk = blockIdx.y (64 chunks)
  if (tw == 0) {
    partial[((size_t)blockIdx.y * 8 + b) * 768 + c0 + tl] =
        red[0][tl] + red[1][tl] + red[2][tl] + red[3][tl];
  }
  float* dst = xT + ((size_t)b * 768 + c0) * 4096 + n0;
  #pragma unroll
  for (int j = 0; j < 16; ++j) {
    const int cc = j * 4 + tw;
    dst[(size_t)cc * 4096 + tl] = tile[tl][cc];
  }
}

__global__ void pool_reduce_kernel(const float* __restrict__ partial, float* __restrict__ pooled) {
  const int idx = blockIdx.x * 256 + threadIdx.x;   // 0..6143 = b*768+c
  float s = 0.0f;
  #pragma unroll
  for (int j = 0; j < 64; ++j) s += partial[(size_t)j * 6144 + idx];
  pooled[idx] = s * (1.0f / 4096.0f);
}

// ---------------- diffusion gate ----------------
__global__ void gamma_kernel(const float* __restrict__ pooled, const float* __restrict__ Wg,
                             const float* __restrict__ bg, float* __restrict__ gamma) {
  const int lane = threadIdx.x & 63;
  const int w = threadIdx.x >> 6;
  const int o = blockIdx.x * 4 + w;
  const int b = o / 768;
  const int j = o - b * 768;
  const float* pr = pooled + b * 768;
  const float* wr = Wg + (size_t)j * 768;
  float s = 0.0f;
  #pragma unroll
  for (int c = lane; c < 768; c += 64) s += pr[c] * wr[c];
  #pragma unroll
  for (int off = 32; off > 0; off >>= 1) s += __shfl_down(s, off);
  if (lane == 0) {
    float gin = s + bg[j];
    gamma[o] = fminf(softplusf(gin), 0.05f);
  }
}

// ---------------- W_out -> bf16 ----------------
__global__ void cvt_bf16_kernel(const float* __restrict__ src, unsigned short* __restrict__ dst, int n) {
  int i = blockIdx.x * 256 + threadIdx.x;
  if (i < n) dst[i] = f2bf(src[i]);
}

// ---------------- symplectic reaction-diffusion PDE (wave-per-channel) ------
// ONLY change vs the 310.7us-verified version: __launch_bounds__(256, 1)
// (was (256,2)) — lets u[64]/v[64] live fully in arch VGPRs instead of
// AGPR-banked with v_accvgpr bounces (VGPR_Count was 108 < the 128 floats).
__global__ __launch_bounds__(256, 1) void pde_kernel(
    const float* __restrict__ xT, const float* __restrict__ gamma,
    const float* __restrict__ alpha, const float* __restrict__ beta,
    const int* __restrict__ kp, unsigned short* __restrict__ uv) {
  const int w = threadIdx.x >> 6;          // wave 0..3 (independent channels)
  const int lane = threadIdx.x & 63;
  const int cidx = blockIdx.x * 4 + w;     // 0..6143
  const int b = cidx / 768;
  const int c = cidx - b * 768;
  const int lx = lane & 7;
  const int ly = lane >> 3;

  int ks = *kp; if (ks < 1) ks = 1;
  const float dt = 1.0f / (float)ks;
  const float hdt = 0.5f * dt;
  const float ae = 0.2f * tanhf(alpha[c]);
  const float be = fmaxf(softplusf(beta[c]), 1e-4f);
  const float g = gamma[b * 768 + c];
  const float c1n = -0.5f * dt * g;   // v -= c1*lap  ->  v += c1n*lap
  const float c2p = dt * g;

  const int laneL = (ly << 3) | ((lx + 7) & 7);
  const int laneR = (ly << 3) | ((lx + 1) & 7);
  const int laneU = (((ly + 7) & 7) << 3) | lx;   // holds rows above (row-1)
  const int laneD = (((ly + 1) & 7) << 3) | lx;   // holds rows below (row+1)

  float u[64], v[64];
  const float* xp = xT + ((size_t)b * 768 + c) * 4096;
  #pragma unroll
  for (int r = 0; r < 8; ++r) {
    const float4* src = (const float4*)(xp + (ly * 8 + r) * 64 + lx * 8);
    const float4 a0 = src[0], a1 = src[1];
    u[r * 8 + 0] = a0.x; u[r * 8 + 1] = a0.y; u[r * 8 + 2] = a0.z; u[r * 8 + 3] = a0.w;
    u[r * 8 + 4] = a1.x; u[r * 8 + 5] = a1.y; u[r * 8 + 6] = a1.z; u[r * 8 + 7] = a1.w;
  }
  #pragma unroll
  for (int i = 0; i < 64; ++i) v[i] = 0.0f;

  // G += COEF * lap(F): halo via 32 shfls, interior in-register.
  #define LAP_PHASE(F, G, COEF)                                               \
    {                                                                         \
      float lh[8], rh[8], uh[8], dh[8];                                       \
      _Pragma("unroll")                                                       \
      for (int r = 0; r < 8; ++r) {                                           \
        lh[r] = __shfl(F[r * 8 + 7], laneL);   /* left lane's right col  */   \
        rh[r] = __shfl(F[r * 8 + 0], laneR);   /* right lane's left col  */   \
        uh[r] = __shfl(F[56 + r], laneU);      /* up lane's bottom row, col r */ \
        dh[r] = __shfl(F[r], laneD);           /* down lane's top row, col r  */ \
      }                                                                       \
      _Pragma("unroll")                                                       \
      for (int r = 0; r < 8; ++r) {                                           \
        _Pragma("unroll")                                                     \
        for (int j = 0; j < 8; ++j) {                                         \
          const float lf = (j == 0) ? lh[r] : F[r * 8 + j - 1];               \
          const float rt = (j == 7) ? rh[r] : F[r * 8 + j + 1];               \
          const float up = (r == 0) ? uh[j] : F[(r - 1) * 8 + j];             \
          const float dn = (r == 7) ? dh[j] : F[(r + 1) * 8 + j];             \
          const float lap = (lf + rt) + (up + dn) - 4.0f * F[r * 8 + j];      \
          G[r * 8 + j] = fmaf((COEF), lap, G[r * 8 + j]);                     \
        }                                                                     \
      }                                                                       \
    }

  for (int s = 0; s < ks; ++s) {
    #pragma unroll
    for (int i = 0; i < 64; ++i) {
      const float q = u[i] * u[i] + v[i] * v[i];
      const float rate = fminf(fmaxf(ae - be * q, -1.0f), 1.0f);
      const float t = hdt * rate;
      u[i] = fmaf(t, u[i], u[i]);
      v[i] = fmaf(t, v[i], v[i]);
    }
    LAP_PHASE(u, v, c1n)
    LAP_PHASE(v, u, c2p)
    LAP_PHASE(u, v, c1n)
    #pragma unroll
    for (int i = 0; i < 64; ++i) {
      const float q = u[i] * u[i] + v[i] * v[i];
      const float rate = fminf(fmaxf(ae - be * q, -1.0f), 1.0f);
      const float t = hdt * rate;
      u[i] = fmaf(t, u[i], u[i]);
      v[i] = fmaf(t, v[i], v[i]);
    }
  }
  #undef LAP_PHASE

  // write out channel-major bf16: uv[b][c][n] = u, uv[b][768+c][n] = v
  unsigned short* up_ = uv + ((size_t)b * 1536 + c) * 4096;
  unsigned short* vp_ = up_ + (size_t)768 * 4096;
  #pragma unroll
  for (int r = 0; r < 8; ++r) {
    const int off = (ly * 8 + r) * 64 + lx * 8;
    short8v us, vs;
    #pragma unroll
    for (int j = 0; j < 8; ++j) {
      us[j] = (short)f2bf(u[r * 8 + j]);
      vs[j] = (short)f2bf(v[r * 8 + j]);
    }
    *(short8v*)(up_ + off) = us;
    *(short8v*)(vp_ + off) = vs;
  }
}

// ---------------- transpose uv [8][1536][4096] -> A [32768][1536] ----------------
__global__ void transpose_uv_kernel(const unsigned short* __restrict__ src,
                                    unsigned short* __restrict__ dst) {
  // grid (64, 24, 8), block 256
  __shared__ unsigned short tile[64][66];
  const int n0 = blockIdx.x * 64;
  const int k0 = blockIdx.y * 64;
  const int b = blockIdx.z;
  const int tx = threadIdx.x & 63;
  const int ty = threadIdx.x >> 6;   // 0..3
  const size_t sbase = ((size_t)b * 1536 + k0) * 4096 + n0;
  #pragma unroll
  for (int j = 0; j < 16; ++j) {
    const int k = ty + 4 * j;
    tile[k][tx] = src[sbase + (size_t)k * 4096 + tx];
  }
  __syncthreads();
  const size_t dbase = ((size_t)b * 4096 + n0) * 1536 + k0;
  #pragma unroll
  for (int j = 0; j < 16; ++j) {
    const int n = ty + 4 * j;
    dst[dbase + (size_t)n * 1536 + tx] = tile[tx][n];
  }
}

// ---------------- bf16 MFMA GEMM (thrice-verified ~140us) -------------------
__global__ __launch_bounds__(256) void gemm_kernel(
    const unsigned short* __restrict__ A,   // [32768][1536] bf16
    const unsigned short* __restrict__ Bt,  // [768][1536]  bf16 (W_out, B^T layout)
    const float* __restrict__ x,            // [32768][768]
    const float* __restrict__ Dv,           // [768]
    float* __restrict__ out) {              // [32768][768]
  __shared__ __align__(16) unsigned short Als[2][128 * 64];
  __shared__ __align__(16) unsigned short Bls[2][128 * 64];
  const int tid = threadIdx.x;
  const int lane = tid & 63;
  const int w = tid >> 6;       // wave 0..3
  const int wr = w >> 1;        // wave row (2x2 waves, each 64x64 of C)
  const int wc = w & 1;

  // XCD-chunked remap: id -> (m-block, n-block). 1536 blocks, 8 XCDs.
  const int id = blockIdx.x;
  const int xcd = id & 7;
  const int seq = id >> 3;          // 0..191
  const int nb = seq % 6;
  const int mb = (seq / 6) * 8 + xcd;
  const int m0 = mb * 128;
  const int n0 = nb * 128;

  // staging-side swizzle: lane covers row (lane>>3), phys slot (lane&7);
  // load global logical slot (lane&7)^(lane>>3)
  const int src_col = (((lane & 7) ^ (lane >> 3)) * 8);   // halfwords
  // read-side: quarter-wave q, row-low bits rlow
  const int q = lane >> 4;
  const int rlow = lane & 7;

  float4v acc[4][4];
  #pragma unroll
  for (int a = 0; a < 4; ++a)
    #pragma unroll
    for (int bq = 0; bq < 4; ++bq)
      acc[a][bq] = (float4v){0.f, 0.f, 0.f, 0.f};

  // per-wave: 8 global_load_lds (4 A + 4 B), 16B each
  #define STAGE(bufi, kbase)                                                  \
    _Pragma("unroll")                                                         \
    for (int i = 0; i < 4; ++i) {                                             \
      const int rowblk = (w * 4 + i) * 8;                                     \
      const int row = rowblk + (lane >> 3);                                   \
      const int kk = (kbase) + src_col;                                       \
      __builtin_amdgcn_global_load_lds(                                       \
          (const __attribute__((address_space(1))) void*)(A + (size_t)(m0 + row) * 1536 + kk), \
          (__attribute__((address_space(3))) void*)(&Als[bufi][rowblk * 64]), 16, 0, 0); \
      __builtin_amdgcn_global_load_lds(                                       \
          (const __attribute__((address_space(1))) void*)(Bt + (size_t)(n0 + row) * 1536 + kk), \
          (__attribute__((address_space(3))) void*)(&Bls[bufi][rowblk * 64]), 16, 0, 0); \
    }

  STAGE(0, 0)
  int cur = 0;
  for (int kt = 0; kt < 24; ++kt) {
    // bar1: all waves' reads of buf[cur^1] retired -> safe to re-stage
    __builtin_amdgcn_s_barrier();
    if (kt < 23) {
      STAGE(cur ^ 1, (kt + 1) * 64)
      asm volatile("s_waitcnt vmcnt(8)" ::: "memory");   // wait prev 8, keep new 8 in flight
    } else {
      asm volatile("s_waitcnt vmcnt(0)" ::: "memory");   // last tile: drain
    }
    // bar2: every wave has its current buffer's loads complete
    __builtin_amdgcn_s_barrier();
    __builtin_amdgcn_sched_barrier(0);
    #pragma unroll
    for (int ksub = 0; ksub < 2; ++ksub) {
      const int soff = ((ksub * 4 + q) ^ rlow) * 8;    // swizzled 16B slot (halfwords)
      short8v af[4], bf[4];
      #pragma unroll
      for (int mi = 0; mi < 4; ++mi)
        af[mi] = *(const short8v*)(&Als[cur][(wr * 64 + mi * 16 + (lane & 15)) * 64 + soff]);
      #pragma unroll
      for (int ni = 0; ni < 4; ++ni)
        bf[ni] = *(const short8v*)(&Bls[cur][(wc * 64 + ni * 16 + (lane & 15)) * 64 + soff]);
      #pragma unroll
      for (int mi = 0; mi < 4; ++mi)
        #pragma unroll
        for (int ni = 0; ni < 4; ++ni)
          acc[mi][ni] = __builtin_amdgcn_mfma_f32_16x16x32_bf16(af[mi], bf[ni], acc[mi][ni], 0, 0, 0);
    }
    cur ^= 1;
  }
  #undef STAGE

  // epilogue: out = acc + x*D  (C/D layout: col=lane&15, row=(lane>>4)*4+r)
  #pragma unroll
  for (int ni = 0; ni < 4; ++ni) {
    const int col = n0 + wc * 64 + ni * 16 + (lane & 15);
    const float dcol = Dv[col];
    #pragma unroll
    for (int mi = 0; mi < 4; ++mi) {
      #pragma unroll
      for (int r = 0; r < 4; ++r) {
        const int row = m0 + wr * 64 + mi * 16 + (lane >> 4) * 4 + r;
        const size_t idx = (size_t)row * 768 + col;
        out[idx] = acc[mi][ni][r] + x[idx] * dcol;
      }
    }
  }
}

// ---------------------------------------------------------------------------
extern "C" void kernel_launch(void* const* d_in, const int* in_sizes, int n_in,
                              void* d_out, int out_size, void* d_ws, size_t ws_size,
                              hipStream_t stream) {
  const float* x     = (const float*)d_in[0];
  const float* Wg    = (const float*)d_in[1];
  const float* bg    = (const float*)d_in[2];
  const float* alpha = (const float*)d_in[3];
  const float* beta  = (const float*)d_in[4];
  const float* Wout  = (const float*)d_in[5];
  const float* Dv    = (const float*)d_in[6];
  const int*   kp    = (const int*)d_in[7];
  float* out = (float*)d_out;

  // workspace layout (~195 MiB)
  //   xT  aliases A   (xT dead before A is written by transpose_uv)
  //   partial aliases uv (partial consumed by pool_reduce before pde writes uv)
  char* ws = (char*)d_ws;
  unsigned short* A   = (unsigned short*)(ws);                 // 32768*1536*2   = 100663296
  float* xT           = (float*)(ws);                          // 8*768*4096*4   (alias A)
  unsigned short* uv  = (unsigned short*)(ws + 100663296);     // 8*1536*4096*2  = 100663296
  float* partial      = (float*)(ws + 100663296);              // 64*8*768*4     (alias uv)
  unsigned short* Wb  = (unsigned short*)(ws + 201326592);     // 768*1536*2     = 2359296
  float* pooled       = (float*)(ws + 203685888);              // 6144*4
  float* gam          = (float*)(ws + 203710464);              // 6144*4

  transpose_x_kernel<<<dim3(12, 64, 8), 256, 0, stream>>>(x, xT, partial);
  pool_reduce_kernel<<<24, 256, 0, stream>>>(partial, pooled);
  gamma_kernel<<<1536, 256, 0, stream>>>(pooled, Wg, bg, gam);
  cvt_bf16_kernel<<<(768 * 1536 + 255) / 256, 256, 0, stream>>>(Wout, Wb, 768 * 1536);
  pde_kernel<<<1536, 256, 0, stream>>>(xT, gam, alpha, beta, kp, uv);
  transpose_uv_kernel<<<dim3(64, 24, 8), 256, 0, stream>>>(uv, A);
  gemm_kernel<<<1536, 256, 0, stream>>>(A, Wb, x, Dv, out);
}